// Round 11
// baseline (219.921 us; speedup 1.0000x reference)
//
#include <hip/hip_runtime.h>
#include <stdint.h>

#define NB 4096   // query rows
#define NM 8192   // memory rows
#define ND 1024   // feature dim

typedef __attribute__((ext_vector_type(8))) short bf16x8;
typedef __attribute__((ext_vector_type(4))) float f32x4;
typedef __attribute__((ext_vector_type(8))) unsigned short u16x8;

static __device__ __forceinline__ unsigned short f2bf(float f) {
  union { float f; uint32_t u; } v; v.f = f;
  uint32_t u = v.u;
  u += 0x7fffu + ((u >> 16) & 1u);   // RNE
  return (unsigned short)(u >> 16);
}
static __device__ __forceinline__ float bf2f(unsigned short b) {
  union { uint32_t u; float f; } v; v.u = ((uint32_t)b) << 16; return v.f;
}

static __device__ __forceinline__ void gload_lds16(const void* g, void* l) {
  __builtin_amdgcn_global_load_lds(
      (__attribute__((address_space(1))) void*)g,
      (__attribute__((address_space(3))) void*)l, 16, 0, 0);
}

#define BAR()   __builtin_amdgcn_s_barrier()
#define LGKM0() asm volatile("s_waitcnt lgkmcnt(0)" ::: "memory")
#define LGKM8() asm volatile("s_waitcnt lgkmcnt(8)" ::: "memory")
#define VMC4()  asm volatile("s_waitcnt vmcnt(4)" ::: "memory")
#define VMC0()  asm volatile("s_waitcnt vmcnt(0)" ::: "memory")

// ---- L2-normalize rows of x [rows x 1024] fp32 -> bf16 out -----------------
__global__ void nrm_kernel(const float* __restrict__ x, unsigned short* __restrict__ out) {
  const int row = blockIdx.x, t = threadIdx.x;
  const float4 v = ((const float4*)(x + (size_t)row * ND))[t];
  float ss = v.x * v.x + v.y * v.y + v.z * v.z + v.w * v.w;
  #pragma unroll
  for (int o = 32; o > 0; o >>= 1) ss += __shfl_xor(ss, o);
  __shared__ float red[4];
  if ((t & 63) == 0) red[t >> 6] = ss;
  __syncthreads();
  ss = (red[0] + red[1]) + (red[2] + red[3]);
  const float sc = 1.0f / fmaxf(sqrtf(ss), 1e-12f);
  ushort4 o4;
  o4.x = f2bf(v.x * sc); o4.y = f2bf(v.y * sc);
  o4.z = f2bf(v.z * sc); o4.w = f2bf(v.w * sc);
  ((ushort4*)(out + (size_t)row * ND))[t] = o4;
}

// ---- transpose memn [8192x1024] bf16 -> memt [1024x8192] bf16 --------------
__global__ void tr_kernel(const unsigned short* __restrict__ memn, unsigned short* __restrict__ memt) {
  __shared__ unsigned short Ts[64][66];
  const int t = threadIdx.x;
  const int d0 = blockIdx.x * 64, m0 = blockIdx.y * 64;
  #pragma unroll
  for (int r = 0; r < 2; ++r) {
    const int lrow = r * 32 + (t >> 3);
    const int lcol = (t & 7) * 8;
    u16x8 v = *(const u16x8*)(memn + (size_t)(m0 + lrow) * ND + d0 + lcol);
    #pragma unroll
    for (int j = 0; j < 8; ++j) Ts[lcol + j][lrow] = v[j];
  }
  __syncthreads();
  #pragma unroll
  for (int r = 0; r < 2; ++r) {
    const int orow = r * 32 + (t >> 3);
    const int ocol = (t & 7) * 8;
    u16x8 o;
    #pragma unroll
    for (int j = 0; j < 8; ++j) o[j] = Ts[orow][ocol + j];
    *(u16x8*)(memt + (size_t)(d0 + orow) * NM + m0 + ocol) = o;
  }
}

// ====== 256x256 GEMM, half-tile-granular pipeline (m201 T4 re-derived) ======
// C[M,N] = A[M,K] * B[N,K]^T (both bf16 row-major, ld = K stride).
// 512 thr = 8 waves (2M x 4N), per-wave 128x64 out, BK=64, dbuf LDS 128 KiB.
// Swizzle: phys_cb = cb ^ ((row&7)<<4); pre-swizzled global src + ds_read.
// Fragment rows: A row = m*32 + wr*16 + lr (alo=A-h0, ahi=A-h1 for all waves);
// B row = nf*64 + wc*16 + lr (blo=B-h0, bhi=B-h1).
// r11: HALF-TILE granular staging/drains (the piece r6-r10 lacked):
//  per phase stage ONE half-tile of T+1 (order A0,B0,B1,A1 -> 3-4 phase lag),
//  counted VMC4 at ends of ph1/ph2/ph4 drains exactly the one half-tile the
//  NEXT phase reads. Gray quadrants: ph1 Q1(alo,blo)[12 rd], ph2 Q2(alo,bhi)
//  [4 rd], ph3 Q3(ahi,bhi)[8 rd], ph4 Q4(ahi,blo)[0 rd].
// Stage-overwrite audit: A0q@T.ph1 vs last read T-1.ph2 (alo reused Q2 from
// regs; LDS read was ph1) -> >=3 phases; B0q@ph2 vs T-1.ph1; B1q@ph3 vs
// T-1.ph2; A1q@ph4 vs T-1.ph3. All >= 3 barrier-separated phases. Race-free.
// MODE 1: E=exp(C) bf16 + psum row-sums.
// MODE 0: fp32 C partials (split-K) + fused attn write (each block writes its
//         64-row x kchunk slice: attn = bf2f(E)*sinv, E is its L2-hot A-panel).
template<int MODE>
__global__ __launch_bounds__(512, 2) void gemmht(
    const unsigned short* __restrict__ A, const unsigned short* __restrict__ B,
    void* __restrict__ Cv, float* __restrict__ psum,
    const float* __restrict__ sinvp, float* __restrict__ attnp,
    int ld, int ldc, int mt, int tps, int kchunk, unsigned long long cstride)
{
  extern __shared__ char smem[];   // [buf][A 32K | B 32K] x2 = 128 KiB
  const int t = threadIdx.x;
  const int w = t >> 6, l = t & 63;
  const int wr = w >> 2, wc = w & 3;
  const int nwg = gridDim.x, cpx = nwg >> 3;
  const int id = (blockIdx.x & 7) * cpx + (blockIdx.x >> 3);  // XCD swizzle
  const int ksp = id / tps, rem = id % tps;
  const int brow = rem % mt, bcol = rem / mt;
  const int k0 = ksp * kchunk;
  const int nt = kchunk >> 6;          // K-tiles (even)

  const int srow = l >> 3;                       // staging row-in-8-group
  const int scol = ((l & 7) ^ srow) << 3;        // pre-swizzled global col
  const int lr = l & 15, lhi = l >> 4;
  const int swz = (l & 7) << 4;
  const int cbk0 = (lhi * 16) ^ swz;
  const int cbk1 = (64 + lhi * 16) ^ swz;
  const int aoffr = (wr * 16 + lr) * 128;        // + m*4096
  const int boffr = (wc * 16 + lr) * 128;        // + nf*8192

  const unsigned short* Ab = A + (size_t)(brow * 256 + w * 8 + srow) * ld + k0 + scol;
  const unsigned short* Bb = B + (size_t)(bcol * 256 + w * 8 + srow) * ld + k0 + scol;

  auto stageA = [&](int p, int h, int tau) {     // one half-tile = 2 gloads
    const int kt = (tau < nt ? tau : nt - 1) << 6;
    const unsigned short* g = Ab + (size_t)(h * 128) * ld + kt;
    char* d = smem + p * 65536 + h * 16384 + w * 1024;
    gload_lds16(g, d);
    gload_lds16(g + (size_t)64 * ld, d + 8192);
  };
  auto stageB = [&](int p, int h, int tau) {
    const int kt = (tau < nt ? tau : nt - 1) << 6;
    const unsigned short* g = Bb + (size_t)(h * 128) * ld + kt;
    char* d = smem + p * 65536 + 32768 + h * 16384 + w * 1024;
    gload_lds16(g, d);
    gload_lds16(g + (size_t)64 * ld, d + 8192);
  };
  auto ldA = [&](int p, int m, int kk) -> bf16x8 {   // A row m*32+wr*16+lr
    return *(const bf16x8*)(smem + p * 65536 + m * 4096 + aoffr + (kk ? cbk1 : cbk0));
  };
  auto ldB = [&](int p, int nf, int kk) -> bf16x8 {  // B row nf*64+wc*16+lr
    return *(const bf16x8*)(smem + p * 65536 + 32768 + nf * 8192 + boffr + (kk ? cbk1 : cbk0));
  };

  f32x4 acc[8][4] = {};
  bf16x8 alo[4][2], ahi[4][2], blo[2][2], bhi[2][2];

  #define CL(AF, BF, MO, NO)                                                   \
    __builtin_amdgcn_s_setprio(1);                                             \
    _Pragma("unroll")                                                          \
    for (int kk = 0; kk < 2; ++kk)                                             \
      _Pragma("unroll")                                                        \
      for (int m = 0; m < 4; ++m)                                              \
        _Pragma("unroll")                                                      \
        for (int n = 0; n < 2; ++n)                                            \
          acc[MO + m][NO + n] = __builtin_amdgcn_mfma_f32_16x16x32_bf16(       \
              AF[m][kk], BF[n][kk], acc[MO + m][NO + n], 0, 0, 0);             \
    __builtin_amdgcn_s_setprio(0);

  // prologue: stage tile0 half-tiles in read-order A0,B0,B1,A1; VMC4 -> A0,B0.
  stageA(0, 0, 0); stageB(0, 0, 0); stageB(0, 1, 0); stageA(0, 1, 0);
  VMC4();
  BAR();

  auto tile_body = [&](int p, int q, int tau) {
    // ---- ph1: reads Q1 (alo 8 + blo 4); stage A-h0(T+1); MFMA Q1
    #pragma unroll
    for (int m = 0; m < 4; ++m) { alo[m][0] = ldA(p, m, 0); alo[m][1] = ldA(p, m, 1); }
    #pragma unroll
    for (int n = 0; n < 2; ++n) { blo[n][0] = ldB(p, n, 0); blo[n][1] = ldB(p, n, 1); }
    stageA(q, 0, tau);
    LGKM8();
    BAR(); LGKM0();
    CL(alo, blo, 0, 0);
    VMC4();             // drains B-h1(p) (staged 3 phases ago) for ph2 reads
    BAR();
    // ---- ph2: reads Q2 (bhi 4); stage B-h0(T+1); MFMA Q2
    #pragma unroll
    for (int n = 0; n < 2; ++n) { bhi[n][0] = ldB(p, 2 + n, 0); bhi[n][1] = ldB(p, 2 + n, 1); }
    stageB(q, 0, tau);
    BAR(); LGKM0();
    CL(alo, bhi, 0, 2);
    VMC4();             // drains A-h1(p) for ph3 reads
    BAR();
    // ---- ph3: reads Q3 (ahi 8); stage B-h1(T+1); MFMA Q3
    #pragma unroll
    for (int m = 0; m < 4; ++m) { ahi[m][0] = ldA(p, 4 + m, 0); ahi[m][1] = ldA(p, 4 + m, 1); }
    stageB(q, 1, tau);
    BAR(); LGKM0();
    CL(ahi, bhi, 4, 2);
    BAR();              // no drain: ph4 reads nothing
    // ---- ph4: no reads; stage A-h1(T+1); MFMA Q4
    stageA(q, 1, tau);
    BAR();
    CL(ahi, blo, 4, 0);
    VMC4();             // drains A-h0(q)+B-h0(q) for next tile's ph1 reads
    BAR();
  };

  const int niter = nt >> 1;
  for (int i = 0; i < niter; ++i) {
    tile_body(0, 1, 2 * i + 1);
    tile_body(1, 0, 2 * i + 2);
  }
  #undef CL

  // epilogue: C row = brow*256 + m*32 + wr*16 + lhi*4 + j,
  //           C col = bcol*256 + n*64 + wc*16 + lr     [m89/m91 C/D map]
  const int crow0 = brow * 256 + wr * 16 + lhi * 4;
  const int ccol0 = bcol * 256 + wc * 16 + lr;
  if constexpr (MODE == 1) {
    // E = exp(sim) bf16 + per-block row-sum partials (deterministic)
    unsigned short* Cp = (unsigned short*)Cv;
    float rs[8][4];
    #pragma unroll
    for (int m = 0; m < 8; ++m)
      #pragma unroll
      for (int j = 0; j < 4; ++j) rs[m][j] = 0.f;
    #pragma unroll
    for (int m = 0; m < 8; ++m)
      #pragma unroll
      for (int n = 0; n < 4; ++n)
        #pragma unroll
        for (int j = 0; j < 4; ++j) {
          const float e = __expf(acc[m][n][j]);
          rs[m][j] += e;
          Cp[(size_t)(crow0 + m * 32 + j) * ldc + ccol0 + n * 64] = f2bf(e);
        }
    #pragma unroll
    for (int m = 0; m < 8; ++m)
      #pragma unroll
      for (int j = 0; j < 4; ++j)
        #pragma unroll
        for (int o = 1; o < 16; o <<= 1) rs[m][j] += __shfl_xor(rs[m][j], o);
    VMC0();            // in-flight clamped stages still write smem
    __syncthreads();
    float* ls = (float*)smem;   // [wc][256 rows] = 4 KiB
    if (lr == 0) {
      #pragma unroll
      for (int m = 0; m < 8; ++m)
        #pragma unroll
        for (int j = 0; j < 4; ++j)
          ls[wc * 256 + wr * 16 + m * 32 + lhi * 4 + j] = rs[m][j];
    }
    __syncthreads();
    if (t < 256) {
      const float s4 = ls[t] + ls[256 + t] + ls[512 + t] + ls[768 + t];
      psum[(size_t)bcol * NB + brow * 256 + t] = s4;
    }
  } else {
    float* Cp = (float*)Cv + (unsigned long long)ksp * cstride;
    #pragma unroll
    for (int m = 0; m < 8; ++m)
      #pragma unroll
      for (int n = 0; n < 4; ++n)
        #pragma unroll
        for (int j = 0; j < 4; ++j)
          Cp[(size_t)(crow0 + m * 32 + j) * ldc + ccol0 + n * 64] = acc[m][n][j];
    // ---- fused attn write: this block's 64-row x kchunk slice -------------
    // rows r0..r0+63 where r0 = brow*256 + bcol*64; cols k0..k0+kchunk.
    if (sinvp != nullptr) {
      const int r0 = brow * 256 + bcol * 64;
      const unsigned short* Ea = A;   // E itself (A operand of this GEMM)
      const int nch = kchunk >> 3;    // u16x8 chunks per row
      for (int idx = t; idx < 64 * nch; idx += 512) {
        const int row = idx / nch, ch = idx % nch;
        const float inv = sinvp[r0 + row];
        u16x8 bv = *(const u16x8*)(Ea + (size_t)(r0 + row) * ld + k0 + ch * 8);
        float4 f0, f1;
        #pragma unroll
        for (int j = 0; j < 8; ++j) {
          const float a = bf2f(bv[j]) * inv;
          if (j < 4) (&f0.x)[j] = a; else (&f1.x)[j - 4] = a;
        }
        float* arow = attnp + (size_t)(r0 + row) * NM + k0 + ch * 8;
        *(float4*)arow = f0;
        *(float4*)(arow + 4) = f1;
      }
    }
  }
}

// ---- sinv: 1/rowsum from psum[32][NB] --------------------------------------
__global__ void sinv_kernel(const float* __restrict__ psum, float* __restrict__ sinv) {
  const int row = blockIdx.x * 256 + threadIdx.x;
  float s = 0.f;
  #pragma unroll
  for (int k = 0; k < 32; ++k) s += psum[(size_t)k * NB + row];
  sinv[row] = 1.0f / s;
}

// ---- reduce partials: mf = (sum_k part[k]) * sinv[row], S = 4 --------------
__global__ void reduce_kernel(const float4* __restrict__ part, float4* __restrict__ mf,
                              const float* __restrict__ sinv) {
  const size_t n4 = (size_t)NB * ND / 4;
  for (size_t i = (size_t)blockIdx.x * blockDim.x + threadIdx.x; i < n4;
       i += (size_t)gridDim.x * blockDim.x) {
    const float is = sinv[i >> 8];   // 256 float4 per row
    float4 s = part[i];
    #pragma unroll
    for (int k = 1; k < 4; ++k) {
      float4 p = part[(size_t)k * n4 + i];
      s.x += p.x; s.y += p.y; s.z += p.z; s.w += p.w;
    }
    s.x *= is; s.y *= is; s.z *= is; s.w *= is;
    mf[i] = s;
  }
}

extern "C" void kernel_launch(void* const* d_in, const int* in_sizes, int n_in,
                              void* d_out, int out_size, void* d_ws, size_t ws_size,
                              hipStream_t stream) {
  const float* q   = (const float*)d_in[0];
  const float* mem = (const float*)d_in[1];
  float* mf   = (float*)d_out;                       // [4096 x 1024]
  float* attn = (float*)d_out + (size_t)NB * ND;     // [4096 x 8192]
  char* ws = (char*)d_ws;
  unsigned short* qn   = (unsigned short*)(ws);                        // 8 MiB
  unsigned short* memn = (unsigned short*)(ws + ((size_t)8  << 20));   // 16 MiB
  unsigned short* memt = (unsigned short*)(ws + ((size_t)24 << 20));   // 16 MiB
  unsigned short* E    = (unsigned short*)(ws + ((size_t)40 << 20));   // 64 MiB
  float* psum          = (float*)(ws + ((size_t)104 << 20));           // 512 KiB
  float* sinv          = (float*)(ws + ((size_t)104 << 20) + (512 << 10)); // 16 KiB
  float* part          = (float*)(ws + ((size_t)105 << 20));           // 64 MiB

  hipFuncSetAttribute((const void*)gemmht<1>,
                      hipFuncAttributeMaxDynamicSharedMemorySize, 131072);
  hipFuncSetAttribute((const void*)gemmht<0>,
                      hipFuncAttributeMaxDynamicSharedMemorySize, 131072);

  hipLaunchKernelGGL(nrm_kernel, dim3(NM), dim3(256), 0, stream, mem, memn);
  hipLaunchKernelGGL(nrm_kernel, dim3(NB), dim3(256), 0, stream, q, qn);
  hipLaunchKernelGGL(tr_kernel, dim3(ND / 64, NM / 64), dim3(256), 0, stream, memn, memt);

  // E = exp(qn * memn^T) bf16 + psum : M=4096, N=8192, K=1024; 512 tiles.
  hipLaunchKernelGGL((gemmht<1>), dim3((NB / 256) * (NM / 256)), dim3(512), 131072, stream,
                     qn, memn, (void*)E, psum, (const float*)nullptr, (float*)nullptr,
                     ND, NM, NB / 256, (NB / 256) * (NM / 256), ND, 0ULL);

  // sinv[row] = 1 / sum_k psum[k][row]
  hipLaunchKernelGGL(sinv_kernel, dim3(NB / 256), dim3(256), 0, stream, psum, sinv);

  // part[k] = E * memt^T (k-slice) + fused attn write (E * sinv, fp32)
  const int tps = (NB / 256) * (ND / 256);   // 64
  hipLaunchKernelGGL((gemmht<0>), dim3(tps * 4), dim3(512), 131072, stream,
                     E, memt, (void*)part, (float*)nullptr, sinv, attn,
                     NM, ND, NB / 256, tps, NM / 4, (unsigned long long)NB * ND);
  hipLaunchKernelGGL(reduce_kernel, dim3(2048), dim3(256), 0, stream,
                     (const float4*)part, (float4*)mf, sinv);
}